// Round 1
// baseline (820.721 us; speedup 1.0000x reference)
//
#include <hip/hip_runtime.h>
#include <hip/hip_bf16.h>

#define S_LEN 1028
#define DH 64
#define NHEAD 16
#define NBATCH 8
#define L2N 3969
#define HIDN 32

typedef __bf16 bf16x8 __attribute__((ext_vector_type(8)));
typedef float f32x4 __attribute__((ext_vector_type(4)));

__device__ __forceinline__ bf16x8 cvt_bf16x8(float4 a, float4 b) {
  bf16x8 r;
  r[0] = (__bf16)a.x; r[1] = (__bf16)a.y; r[2] = (__bf16)a.z; r[3] = (__bf16)a.w;
  r[4] = (__bf16)b.x; r[5] = (__bf16)b.y; r[6] = (__bf16)b.z; r[7] = (__bf16)b.w;
  return r;
}

__device__ __forceinline__ f32x4 mfma16(bf16x8 a, bf16x8 b, f32x4 c) {
  return __builtin_amdgcn_mfma_f32_16x16x32_bf16(a, b, c, 0, 0, 0);
}

// ---------------- Kernel 1: CPB bias table bt[h][L2] ----------------
__global__ void cpb_table_kernel(const float* __restrict__ rel,
                                 const float* __restrict__ W1,
                                 const float* __restrict__ b1,
                                 const float* __restrict__ W2,
                                 float* __restrict__ bt) {
  int i = blockIdx.x * blockDim.x + threadIdx.x;
  if (i >= L2N) return;
  float x = rel[2 * i], y = rel[2 * i + 1];
  float acc[NHEAD];
#pragma unroll
  for (int h = 0; h < NHEAD; ++h) acc[h] = 0.f;
#pragma unroll
  for (int j = 0; j < HIDN; ++j) {
    float t = fmaf(x, W1[j], fmaf(y, W1[HIDN + j], b1[j]));
    float g = 0.5f * t * (1.f + erff(t * 0.70710678118654752f));  // exact GELU
#pragma unroll
    for (int h = 0; h < NHEAD; ++h) acc[h] = fmaf(g, W2[j * NHEAD + h], acc[h]);
  }
#pragma unroll
  for (int h = 0; h < NHEAD; ++h) bt[h * L2N + i] = acc[h];
}

// ---------------- Kernel 2: flash attention with CPB bias ----------------
// block = 256 threads = 4 waves; each block: one (b,h,q-tile of 64 rows);
// wave w owns q rows [qt*64 + w*16, +16). KV iterated in tiles of 32.
__global__ __launch_bounds__(256) void flex_attn_kernel(
    const float* __restrict__ qg, const float* __restrict__ kg,
    const float* __restrict__ vg, const int* __restrict__ idx_table,
    const float* __restrict__ bt, const int* __restrict__ Rp,
    float* __restrict__ out) {
  const int R = Rp[0];
  const int b = blockIdx.z, h = blockIdx.y, qt = blockIdx.x;
  const int tid = threadIdx.x;
  const int wave = tid >> 6, lane = tid & 63;
  const int g = lane >> 4, m = lane & 15;

  // LDS: bias row for this head + K tile + V^T tile + per-wave P scratch.
  // Pitches (72, 40) chosen so ds_read_b128 fragment reads are <=2-way bank aliased.
  __shared__ __align__(16) float bt_h[L2N];
  __shared__ __align__(16) __bf16 Kt[32][72];
  __shared__ __align__(16) __bf16 Vt[64][40];
  __shared__ __align__(16) __bf16 Pl[4][16][40];

  for (int i = tid; i < L2N; i += 256) bt_h[i] = bt[h * L2N + i];

  const size_t base = ((size_t)(b * NHEAD + h)) * S_LEN * DH;
  const float* qp = qg + base;
  const float* kp = kg + base;
  const float* vp = vg + base;

  // Q fragments for this lane: A-layout row = lane&15, k = 8*(lane>>4)+j
  const int qrow = qt * 64 + wave * 16 + m;
  bf16x8 qf[2];
#pragma unroll
  for (int dc = 0; dc < 2; ++dc) {
    float4 a = {0.f, 0.f, 0.f, 0.f}, bb = {0.f, 0.f, 0.f, 0.f};
    if (qrow < S_LEN) {
      a = *(const float4*)(qp + (size_t)qrow * DH + dc * 32 + g * 8);
      bb = *(const float4*)(qp + (size_t)qrow * DH + dc * 32 + g * 8 + 4);
    }
    qf[dc] = cvt_bf16x8(a, bb);
  }

  f32x4 acc_o[4];
#pragma unroll
  for (int t = 0; t < 4; ++t) acc_o[t] = (f32x4){0.f, 0.f, 0.f, 0.f};
  float mrow[4], lrow[4];
#pragma unroll
  for (int r = 0; r < 4; ++r) { mrow[r] = -1e30f; lrow[r] = 0.f; }

  const int qb4 = qt * 64 + wave * 16 + g * 4;  // C/D row base for this lane
  const int nkt = (S_LEN + 31) / 32;            // 33

  for (int it = 0; it < nkt; ++it) {
    const int kb = it * 32;
    __syncthreads();  // previous iteration's LDS reads complete

    // ---- stage K tile [32 keys][64 d] (bf16, pitch 72) ----
    {
      const int key = wave * 8 + (lane >> 3);
      const int dblk = lane & 7;
      const int krow = kb + key;
      float4 a = {0.f, 0.f, 0.f, 0.f}, bb = {0.f, 0.f, 0.f, 0.f};
      if (krow < S_LEN) {
        a = *(const float4*)(kp + (size_t)krow * DH + dblk * 8);
        bb = *(const float4*)(kp + (size_t)krow * DH + dblk * 8 + 4);
      }
      *(bf16x8*)&Kt[key][dblk * 8] = cvt_bf16x8(a, bb);
    }
    // ---- stage V^T tile [64 d][32 keys] (bf16, pitch 40) ----
    {
      bf16x8 pv;
#pragma unroll
      for (int t = 0; t < 8; ++t) {
        const int krow = kb + wave * 8 + t;
        pv[t] = (krow < S_LEN) ? (__bf16)vp[(size_t)krow * DH + lane] : (__bf16)0.f;
      }
      *(bf16x8*)&Vt[lane][wave * 8] = pv;
    }

    // ---- bias gather (overlaps staging latency; needs only bt_h) ----
    float bias[2][4];
    bool kval[2];
#pragma unroll
    for (int c = 0; c < 2; ++c) {
      const int key = kb + c * 16 + m;
      kval[c] = (key < S_LEN);
      const int keyc = min(key, S_LEN - 1);
#pragma unroll
      for (int r = 0; r < 4; ++r) {
        const int qq = qb4 + r;
        const int qc = min(qq, S_LEN - 1);
        float bv = 0.f;
        if (qq >= R && key >= R && kval[c])
          bv = bt_h[idx_table[(size_t)qc * S_LEN + keyc]];
        bias[c][r] = bv;
      }
    }

    __syncthreads();  // staging visible

    // ---- QK^T: two 16x16 key tiles, K-dim = 64 = 2 MFMAs each ----
    f32x4 sc[2];
#pragma unroll
    for (int c = 0; c < 2; ++c) {
      f32x4 accs = (f32x4){0.f, 0.f, 0.f, 0.f};
#pragma unroll
      for (int dc = 0; dc < 2; ++dc) {
        bf16x8 kf = *(bf16x8*)&Kt[c * 16 + m][dc * 32 + g * 8];
        accs = mfma16(qf[dc], kf, accs);
      }
      sc[c] = accs;
    }

    // ---- online softmax over this 32-key tile ----
    float pbuf[2][4];
#pragma unroll
    for (int r = 0; r < 4; ++r) {
      float s0 = kval[0] ? fmaf(sc[0][r], 0.125f, bias[0][r]) : -1e30f;
      float s1 = kval[1] ? fmaf(sc[1][r], 0.125f, bias[1][r]) : -1e30f;
      float mx = fmaxf(s0, s1);
      mx = fmaxf(mx, __shfl_xor(mx, 1));
      mx = fmaxf(mx, __shfl_xor(mx, 2));
      mx = fmaxf(mx, __shfl_xor(mx, 4));
      mx = fmaxf(mx, __shfl_xor(mx, 8));
      const float mnew = fmaxf(mrow[r], mx);
      const float alpha = __expf(mrow[r] - mnew);
      const float p0 = __expf(s0 - mnew);
      const float p1 = __expf(s1 - mnew);
      float sum = p0 + p1;
      sum += __shfl_xor(sum, 1);
      sum += __shfl_xor(sum, 2);
      sum += __shfl_xor(sum, 4);
      sum += __shfl_xor(sum, 8);
      lrow[r] = lrow[r] * alpha + sum;
      mrow[r] = mnew;
      pbuf[0][r] = p0;
      pbuf[1][r] = p1;
#pragma unroll
      for (int t = 0; t < 4; ++t) acc_o[t][r] *= alpha;
    }

    // ---- write P (bf16) to per-wave LDS, packed pairs ----
#pragma unroll
    for (int c = 0; c < 2; ++c) {
#pragma unroll
      for (int r = 0; r < 4; ++r) {
        float p = pbuf[c][r];
        float po = __shfl_xor(p, 1);
        if (!(lane & 1)) {
          unsigned short lo = __builtin_bit_cast(unsigned short, (__bf16)p);
          unsigned short hi = __builtin_bit_cast(unsigned short, (__bf16)po);
          unsigned int pk = (unsigned int)lo | ((unsigned int)hi << 16);
          *(unsigned int*)&Pl[wave][g * 4 + r][c * 16 + m] = pk;
        }
      }
    }

    // ---- PV: acc_o[t] += P[16x32] * V[32 x 16t] (per-wave, same-wave LDS) ----
    {
      bf16x8 pf = *(bf16x8*)&Pl[wave][m][g * 8];
#pragma unroll
      for (int t = 0; t < 4; ++t) {
        bf16x8 vf = *(bf16x8*)&Vt[t * 16 + m][g * 8];
        acc_o[t] = mfma16(pf, vf, acc_o[t]);
      }
    }
  }

  // ---- epilogue: O = acc / l ----
#pragma unroll
  for (int r = 0; r < 4; ++r) {
    const int qq = qb4 + r;
    if (qq >= S_LEN) continue;
    const float inv = 1.f / lrow[r];
    float* op = out + (((size_t)(b * NHEAD + h)) * S_LEN + qq) * DH;
#pragma unroll
    for (int t = 0; t < 4; ++t) op[t * 16 + m] = acc_o[t][r] * inv;
  }
}

extern "C" void kernel_launch(void* const* d_in, const int* in_sizes, int n_in,
                              void* d_out, int out_size, void* d_ws, size_t ws_size,
                              hipStream_t stream) {
  const float* q = (const float*)d_in[0];
  const float* k = (const float*)d_in[1];
  const float* v = (const float*)d_in[2];
  const float* rel = (const float*)d_in[3];
  const float* W1 = (const float*)d_in[4];
  const float* b1 = (const float*)d_in[5];
  const float* W2 = (const float*)d_in[6];
  const int* idx = (const int*)d_in[7];
  const int* Rp = (const int*)d_in[8];
  float* out = (float*)d_out;
  float* bt = (float*)d_ws;  // [NHEAD][L2N] fp32 = 254 KB

  cpb_table_kernel<<<dim3((L2N + 255) / 256), dim3(256), 0, stream>>>(rel, W1, b1, W2, bt);
  flex_attn_kernel<<<dim3((S_LEN + 63) / 64, NHEAD, NBATCH), dim3(256), 0, stream>>>(
      q, k, v, idx, bt, Rp, out);
}

// Round 2
// 569.381 us; speedup vs baseline: 1.4414x; 1.4414x over previous
//
#include <hip/hip_runtime.h>
#include <hip/hip_bf16.h>

#define S_LEN 1028
#define DH 64
#define NHEAD 16
#define NBATCH 8
#define L2N 3969
#define HIDN 32
#define KVB 64
#define NKT ((S_LEN + KVB - 1) / KVB)   // 17
#define NQT ((S_LEN + 63) / 64)         // 17

typedef __bf16 bf16x8 __attribute__((ext_vector_type(8)));
typedef __bf16 bf16x4 __attribute__((ext_vector_type(4)));
typedef float f32x4 __attribute__((ext_vector_type(4)));

__device__ __forceinline__ bf16x8 cvt_bf16x8(float4 a, float4 b) {
  bf16x8 r;
  r[0] = (__bf16)a.x; r[1] = (__bf16)a.y; r[2] = (__bf16)a.z; r[3] = (__bf16)a.w;
  r[4] = (__bf16)b.x; r[5] = (__bf16)b.y; r[6] = (__bf16)b.z; r[7] = (__bf16)b.w;
  return r;
}

__device__ __forceinline__ f32x4 mfma16(bf16x8 a, bf16x8 b, f32x4 c) {
  return __builtin_amdgcn_mfma_f32_16x16x32_bf16(a, b, c, 0, 0, 0);
}

// ---------------- CPB MLP table, l-major: bt[l][h] (for 64B-granular gather) ----
__global__ void cpb_table_lh(const float* __restrict__ rel,
                             const float* __restrict__ W1,
                             const float* __restrict__ b1,
                             const float* __restrict__ W2,
                             float* __restrict__ bt) {
  int i = blockIdx.x * blockDim.x + threadIdx.x;
  if (i >= L2N) return;
  float x = rel[2 * i], y = rel[2 * i + 1];
  float acc[NHEAD];
#pragma unroll
  for (int h = 0; h < NHEAD; ++h) acc[h] = 0.f;
#pragma unroll
  for (int j = 0; j < HIDN; ++j) {
    float t = fmaf(x, W1[j], fmaf(y, W1[HIDN + j], b1[j]));
    float g = 0.5f * t * (1.f + erff(t * 0.70710678118654752f));
#pragma unroll
    for (int h = 0; h < NHEAD; ++h) acc[h] = fmaf(g, W2[j * NHEAD + h], acc[h]);
  }
#pragma unroll
  for (int h = 0; h < NHEAD; ++h) bt[(size_t)i * NHEAD + h] = acc[h];
}

// ---------------- expand masked bias to bf16 [H][S][S] ----------------
__global__ void bias_expand(const int* __restrict__ idx,
                            const float* __restrict__ bt,
                            const int* __restrict__ Rp,
                            __bf16* __restrict__ bias) {
  const int qrow = blockIdx.x;
  const int R = Rp[0];
  const bool qok = (qrow >= R);
  for (int k = threadIdx.x; k < S_LEN; k += blockDim.x) {
    const int l = idx[(size_t)qrow * S_LEN + k];
    const bool on = qok && (k >= R);
    const float4* btv = (const float4*)bt + (size_t)l * 4;
    float va[16];
    *(float4*)&va[0]  = btv[0];
    *(float4*)&va[4]  = btv[1];
    *(float4*)&va[8]  = btv[2];
    *(float4*)&va[12] = btv[3];
#pragma unroll
    for (int h = 0; h < NHEAD; ++h)
      bias[(size_t)h * S_LEN * S_LEN + (size_t)qrow * S_LEN + k] =
          on ? (__bf16)va[h] : (__bf16)0.f;
  }
}

// ---------------- fast flash attention with precomputed bias ----------------
// 256 thr = 4 waves; block = (b, h, 64 q-rows); KV tiles of 64.
// K rows staged permuted: Kt row rho holds key kb + 4*(rho&15) + (rho>>4),
// so score tile c, col m  <->  key kb + 4m + c. Hence bias and P are
// CONTIGUOUS groups of 4 per lane (bf16x4 load / ds_write, no shuffles).
__global__ __launch_bounds__(256, 4) void flex_attn_fast(
    const float* __restrict__ qg, const float* __restrict__ kg,
    const float* __restrict__ vg, const __bf16* __restrict__ biasG,
    float* __restrict__ out) {
  const int b = blockIdx.z, h = blockIdx.y, qt = blockIdx.x;
  const int tid = threadIdx.x;
  const int wave = tid >> 6, lane = tid & 63;
  const int g = lane >> 4, m = lane & 15;

  __shared__ __align__(16) __bf16 Kt[KVB][72];
  __shared__ __align__(16) __bf16 Vt[DH][72];
  __shared__ __align__(16) __bf16 Pl[4][16][72];

  const size_t base = ((size_t)(b * NHEAD + h)) * S_LEN * DH;
  const float* qp = qg + base;
  const float* kp = kg + base;
  const float* vp = vg + base;
  const __bf16* bp = biasG + (size_t)h * S_LEN * S_LEN;

  // Q fragments, pre-scaled by Dh^-0.5 = 0.125 (exact power of 2)
  const int qrow = qt * 64 + wave * 16 + m;
  bf16x8 qf[2];
#pragma unroll
  for (int dc = 0; dc < 2; ++dc) {
    float4 a = {0.f, 0.f, 0.f, 0.f}, bb = {0.f, 0.f, 0.f, 0.f};
    if (qrow < S_LEN) {
      a = *(const float4*)(qp + (size_t)qrow * DH + dc * 32 + g * 8);
      bb = *(const float4*)(qp + (size_t)qrow * DH + dc * 32 + g * 8 + 4);
    }
    a.x *= 0.125f; a.y *= 0.125f; a.z *= 0.125f; a.w *= 0.125f;
    bb.x *= 0.125f; bb.y *= 0.125f; bb.z *= 0.125f; bb.w *= 0.125f;
    qf[dc] = cvt_bf16x8(a, bb);
  }

  f32x4 acc_o[4];
#pragma unroll
  for (int t = 0; t < 4; ++t) acc_o[t] = (f32x4){0.f, 0.f, 0.f, 0.f};
  float mrow[4], lrow[4];
#pragma unroll
  for (int r = 0; r < 4; ++r) { mrow[r] = -1e30f; lrow[r] = 0.f; }

  const int qb4 = qt * 64 + wave * 16 + g * 4;

  // staging geometry
  const int eK = wave * 16 + (lane >> 2);          // key offset staged (K)
  const int rowK = ((eK & 3) << 4) | (eK >> 2);    // permuted LDS row
  const int colK = (lane & 3) * 16;

  for (int it = 0; it < NKT; ++it) {
    const int kb = it * KVB;
    __syncthreads();  // prev iteration LDS reads done

    // ---- stage K (permuted rows), fp32 -> bf16 ----
    {
      const int krow = kb + eK;
      float4 a0 = {0,0,0,0}, a1 = {0,0,0,0}, a2 = {0,0,0,0}, a3 = {0,0,0,0};
      if (krow < S_LEN) {
        const float* src = kp + (size_t)krow * DH + colK;
        a0 = *(const float4*)(src);
        a1 = *(const float4*)(src + 4);
        a2 = *(const float4*)(src + 8);
        a3 = *(const float4*)(src + 12);
      }
      *(bf16x8*)&Kt[rowK][colK] = cvt_bf16x8(a0, a1);
      *(bf16x8*)&Kt[rowK][colK + 8] = cvt_bf16x8(a2, a3);
    }
    // ---- stage V^T (natural key order) ----
    {
      bf16x8 p0, p1;
#pragma unroll
      for (int t = 0; t < 8; ++t) {
        const int kr = kb + wave * 16 + t;
        p0[t] = (kr < S_LEN) ? (__bf16)vp[(size_t)kr * DH + lane] : (__bf16)0.f;
      }
#pragma unroll
      for (int t = 0; t < 8; ++t) {
        const int kr = kb + wave * 16 + 8 + t;
        p1[t] = (kr < S_LEN) ? (__bf16)vp[(size_t)kr * DH + lane] : (__bf16)0.f;
      }
      *(bf16x8*)&Vt[lane][wave * 16] = p0;
      *(bf16x8*)&Vt[lane][wave * 16 + 8] = p1;
    }

    // ---- bias: keys kb+4m .. kb+4m+3, one bf16x4 per row ----
    const int kk = kb + 4 * m;
    const bool kvalid = (kk < S_LEN);  // group of 4 fully valid or fully not
    bf16x4 bias4[4];
#pragma unroll
    for (int r = 0; r < 4; ++r) {
      const int qq = min(qb4 + r, S_LEN - 1);
      bf16x4 z; z[0] = (__bf16)0.f; z[1] = (__bf16)0.f; z[2] = (__bf16)0.f; z[3] = (__bf16)0.f;
      bias4[r] = kvalid ? *(const bf16x4*)(bp + (size_t)qq * S_LEN + kk) : z;
    }

    __syncthreads();  // staging visible

    // ---- QK^T: 4 column tiles x 2 MFMAs ----
    f32x4 sc[4];
#pragma unroll
    for (int c = 0; c < 4; ++c) {
      f32x4 a = (f32x4){0.f, 0.f, 0.f, 0.f};
#pragma unroll
      for (int dc = 0; dc < 2; ++dc) {
        bf16x8 kf = *(bf16x8*)&Kt[c * 16 + m][dc * 32 + g * 8];
        a = mfma16(qf[dc], kf, a);
      }
      sc[c] = a;
    }

    // ---- online softmax (row r lives in the 16 lanes sharing g) ----
#pragma unroll
    for (int r = 0; r < 4; ++r) {
      float s[4];
#pragma unroll
      for (int c = 0; c < 4; ++c)
        s[c] = kvalid ? sc[c][r] + (float)bias4[r][c] : -1e30f;
      float mx = fmaxf(fmaxf(s[0], s[1]), fmaxf(s[2], s[3]));
      mx = fmaxf(mx, __shfl_xor(mx, 1));
      mx = fmaxf(mx, __shfl_xor(mx, 2));
      mx = fmaxf(mx, __shfl_xor(mx, 4));
      mx = fmaxf(mx, __shfl_xor(mx, 8));
      const float mnew = fmaxf(mrow[r], mx);
      const float alpha = __expf(mrow[r] - mnew);
      float p0 = __expf(s[0] - mnew), p1 = __expf(s[1] - mnew);
      float p2 = __expf(s[2] - mnew), p3 = __expf(s[3] - mnew);
      float sum = (p0 + p1) + (p2 + p3);
      sum += __shfl_xor(sum, 1);
      sum += __shfl_xor(sum, 2);
      sum += __shfl_xor(sum, 4);
      sum += __shfl_xor(sum, 8);
      lrow[r] = lrow[r] * alpha + sum;
      mrow[r] = mnew;
      bf16x4 pb;
      pb[0] = (__bf16)p0; pb[1] = (__bf16)p1; pb[2] = (__bf16)p2; pb[3] = (__bf16)p3;
      *(bf16x4*)&Pl[wave][g * 4 + r][4 * m] = pb;  // col = key offset (4m+c)
#pragma unroll
      for (int t = 0; t < 4; ++t) acc_o[t][r] *= alpha;
    }

    // ---- PV: 2 k-chunks x 4 d-tiles (per-wave P, no barrier needed) ----
#pragma unroll
    for (int kc = 0; kc < 2; ++kc) {
      bf16x8 pf = *(bf16x8*)&Pl[wave][m][kc * 32 + g * 8];
#pragma unroll
      for (int t = 0; t < 4; ++t) {
        bf16x8 vf = *(bf16x8*)&Vt[t * 16 + m][kc * 32 + g * 8];
        acc_o[t] = mfma16(pf, vf, acc_o[t]);
      }
    }
  }

  // ---- epilogue ----
#pragma unroll
  for (int r = 0; r < 4; ++r) {
    const int qq = qb4 + r;
    if (qq >= S_LEN) continue;
    const float inv = 1.f / lrow[r];
    float* op = out + (((size_t)(b * NHEAD + h)) * S_LEN + qq) * DH;
#pragma unroll
    for (int t = 0; t < 4; ++t) op[t * 16 + m] = acc_o[t][r] * inv;
  }
}

// ================= fallback path (round-1, used only if ws too small) =======
__global__ void cpb_table_kernel(const float* __restrict__ rel,
                                 const float* __restrict__ W1,
                                 const float* __restrict__ b1,
                                 const float* __restrict__ W2,
                                 float* __restrict__ bt) {
  int i = blockIdx.x * blockDim.x + threadIdx.x;
  if (i >= L2N) return;
  float x = rel[2 * i], y = rel[2 * i + 1];
  float acc[NHEAD];
#pragma unroll
  for (int h = 0; h < NHEAD; ++h) acc[h] = 0.f;
#pragma unroll
  for (int j = 0; j < HIDN; ++j) {
    float t = fmaf(x, W1[j], fmaf(y, W1[HIDN + j], b1[j]));
    float g = 0.5f * t * (1.f + erff(t * 0.70710678118654752f));
#pragma unroll
    for (int h = 0; h < NHEAD; ++h) acc[h] = fmaf(g, W2[j * NHEAD + h], acc[h]);
  }
#pragma unroll
  for (int h = 0; h < NHEAD; ++h) bt[h * L2N + i] = acc[h];
}

__global__ __launch_bounds__(256) void flex_attn_kernel(
    const float* __restrict__ qg, const float* __restrict__ kg,
    const float* __restrict__ vg, const int* __restrict__ idx_table,
    const float* __restrict__ bt, const int* __restrict__ Rp,
    float* __restrict__ out) {
  const int R = Rp[0];
  const int b = blockIdx.z, h = blockIdx.y, qt = blockIdx.x;
  const int tid = threadIdx.x;
  const int wave = tid >> 6, lane = tid & 63;
  const int g = lane >> 4, m = lane & 15;

  __shared__ __align__(16) float bt_h[L2N];
  __shared__ __align__(16) __bf16 Kt[32][72];
  __shared__ __align__(16) __bf16 Vt[64][40];
  __shared__ __align__(16) __bf16 Pl[4][16][40];

  for (int i = tid; i < L2N; i += 256) bt_h[i] = bt[h * L2N + i];

  const size_t base = ((size_t)(b * NHEAD + h)) * S_LEN * DH;
  const float* qp = qg + base;
  const float* kp = kg + base;
  const float* vp = vg + base;

  const int qrow = qt * 64 + wave * 16 + m;
  bf16x8 qf[2];
#pragma unroll
  for (int dc = 0; dc < 2; ++dc) {
    float4 a = {0.f, 0.f, 0.f, 0.f}, bb = {0.f, 0.f, 0.f, 0.f};
    if (qrow < S_LEN) {
      a = *(const float4*)(qp + (size_t)qrow * DH + dc * 32 + g * 8);
      bb = *(const float4*)(qp + (size_t)qrow * DH + dc * 32 + g * 8 + 4);
    }
    qf[dc] = cvt_bf16x8(a, bb);
  }

  f32x4 acc_o[4];
#pragma unroll
  for (int t = 0; t < 4; ++t) acc_o[t] = (f32x4){0.f, 0.f, 0.f, 0.f};
  float mrow[4], lrow[4];
#pragma unroll
  for (int r = 0; r < 4; ++r) { mrow[r] = -1e30f; lrow[r] = 0.f; }

  const int qb4 = qt * 64 + wave * 16 + g * 4;
  const int nkt = (S_LEN + 31) / 32;

  for (int it = 0; it < nkt; ++it) {
    const int kb = it * 32;
    __syncthreads();
    {
      const int key = wave * 8 + (lane >> 3);
      const int dblk = lane & 7;
      const int krow = kb + key;
      float4 a = {0.f, 0.f, 0.f, 0.f}, bb = {0.f, 0.f, 0.f, 0.f};
      if (krow < S_LEN) {
        a = *(const float4*)(kp + (size_t)krow * DH + dblk * 8);
        bb = *(const float4*)(kp + (size_t)krow * DH + dblk * 8 + 4);
      }
      *(bf16x8*)&Kt[key][dblk * 8] = cvt_bf16x8(a, bb);
    }
    {
      bf16x8 pv;
#pragma unroll
      for (int t = 0; t < 8; ++t) {
        const int krow = kb + wave * 8 + t;
        pv[t] = (krow < S_LEN) ? (__bf16)vp[(size_t)krow * DH + lane] : (__bf16)0.f;
      }
      *(bf16x8*)&Vt[lane][wave * 8] = pv;
    }

    float bias[2][4];
    bool kval[2];
#pragma unroll
    for (int c = 0; c < 2; ++c) {
      const int key = kb + c * 16 + m;
      kval[c] = (key < S_LEN);
      const int keyc = min(key, S_LEN - 1);
#pragma unroll
      for (int r = 0; r < 4; ++r) {
        const int qq = qb4 + r;
        const int qc = min(qq, S_LEN - 1);
        float bv = 0.f;
        if (qq >= R && key >= R && kval[c])
          bv = bt_h[idx_table[(size_t)qc * S_LEN + keyc]];
        bias[c][r] = bv;
      }
    }

    __syncthreads();

    f32x4 sc[2];
#pragma unroll
    for (int c = 0; c < 2; ++c) {
      f32x4 accs = (f32x4){0.f, 0.f, 0.f, 0.f};
#pragma unroll
      for (int dc = 0; dc < 2; ++dc) {
        bf16x8 kf = *(bf16x8*)&Kt[c * 16 + m][dc * 32 + g * 8];
        accs = mfma16(qf[dc], kf, accs);
      }
      sc[c] = accs;
    }

    float pbuf[2][4];
#pragma unroll
    for (int r = 0; r < 4; ++r) {
      float s0 = kval[0] ? fmaf(sc[0][r], 0.125f, bias[0][r]) : -1e30f;
      float s1 = kval[1] ? fmaf(sc[1][r], 0.125f, bias[1][r]) : -1e30f;
      float mx = fmaxf(s0, s1);
      mx = fmaxf(mx, __shfl_xor(mx, 1));
      mx = fmaxf(mx, __shfl_xor(mx, 2));
      mx = fmaxf(mx, __shfl_xor(mx, 4));
      mx = fmaxf(mx, __shfl_xor(mx, 8));
      const float mnew = fmaxf(mrow[r], mx);
      const float alpha = __expf(mrow[r] - mnew);
      const float p0 = __expf(s0 - mnew);
      const float p1 = __expf(s1 - mnew);
      float sum = p0 + p1;
      sum += __shfl_xor(sum, 1);
      sum += __shfl_xor(sum, 2);
      sum += __shfl_xor(sum, 4);
      sum += __shfl_xor(sum, 8);
      lrow[r] = lrow[r] * alpha + sum;
      mrow[r] = mnew;
      pbuf[0][r] = p0;
      pbuf[1][r] = p1;
#pragma unroll
      for (int t = 0; t < 4; ++t) acc_o[t][r] *= alpha;
    }

#pragma unroll
    for (int c = 0; c < 2; ++c) {
#pragma unroll
      for (int r = 0; r < 4; ++r) {
        float p = pbuf[c][r];
        float po = __shfl_xor(p, 1);
        if (!(lane & 1)) {
          unsigned short lo = __builtin_bit_cast(unsigned short, (__bf16)p);
          unsigned short hi = __builtin_bit_cast(unsigned short, (__bf16)po);
          unsigned int pk = (unsigned int)lo | ((unsigned int)hi << 16);
          *(unsigned int*)&Pl[wave][g * 4 + r][c * 16 + m] = pk;
        }
      }
    }

    {
      bf16x8 pf = *(bf16x8*)&Pl[wave][m][g * 8];
#pragma unroll
      for (int t = 0; t < 4; ++t) {
        bf16x8 vf = *(bf16x8*)&Vt[t * 16 + m][g * 8];
        acc_o[t] = mfma16(pf, vf, acc_o[t]);
      }
    }
  }

#pragma unroll
  for (int r = 0; r < 4; ++r) {
    const int qq = qb4 + r;
    if (qq >= S_LEN) continue;
    const float inv = 1.f / lrow[r];
    float* op = out + (((size_t)(b * NHEAD + h)) * S_LEN + qq) * DH;
#pragma unroll
    for (int t = 0; t < 4; ++t) op[t * 16 + m] = acc_o[t][r] * inv;
  }
}

extern "C" void kernel_launch(void* const* d_in, const int* in_sizes, int n_in,
                              void* d_out, int out_size, void* d_ws, size_t ws_size,
                              hipStream_t stream) {
  const float* q = (const float*)d_in[0];
  const float* k = (const float*)d_in[1];
  const float* v = (const float*)d_in[2];
  const float* rel = (const float*)d_in[3];
  const float* W1 = (const float*)d_in[4];
  const float* b1 = (const float*)d_in[5];
  const float* W2 = (const float*)d_in[6];
  const int* idx = (const int*)d_in[7];
  const int* Rp = (const int*)d_in[8];
  float* out = (float*)d_out;

  const size_t bt_bytes = (size_t)L2N * NHEAD * 4;                 // 254 016
  const size_t bias_bytes = (size_t)NHEAD * S_LEN * S_LEN * 2;     // ~33.8 MB

  if (ws_size >= bt_bytes + bias_bytes) {
    float* bt = (float*)d_ws;                                      // [L2N][H]
    __bf16* bias = (__bf16*)((char*)d_ws + bt_bytes);              // [H][S][S]
    cpb_table_lh<<<dim3((L2N + 255) / 256), dim3(256), 0, stream>>>(rel, W1, b1, W2, bt);
    bias_expand<<<dim3(S_LEN), dim3(256), 0, stream>>>(idx, bt, Rp, bias);
    flex_attn_fast<<<dim3(NQT, NHEAD, NBATCH), dim3(256), 0, stream>>>(q, k, v, bias, out);
  } else {
    float* bt = (float*)d_ws;                                      // [H][L2N]
    cpb_table_kernel<<<dim3((L2N + 255) / 256), dim3(256), 0, stream>>>(rel, W1, b1, W2, bt);
    flex_attn_kernel<<<dim3(NQT, NHEAD, NBATCH), dim3(256), 0, stream>>>(q, k, v, idx, bt, Rp, out);
  }
}

// Round 4
// 279.772 us; speedup vs baseline: 2.9335x; 2.0352x over previous
//
#include <hip/hip_runtime.h>
#include <hip/hip_bf16.h>

#define S_LEN 1028
#define DH 64
#define NHEAD 16
#define NBATCH 8
#define L2N 3969
#define HIDN 32
#define KVB 64
#define NKT 17
#define NQT 17
#define TILE_E 4096  // 64x64 elems per packed tile

typedef __bf16 bf16x8 __attribute__((ext_vector_type(8)));
typedef __bf16 bf16x4 __attribute__((ext_vector_type(4)));
typedef float f32x4 __attribute__((ext_vector_type(4)));

__device__ __forceinline__ bf16x8 cvt_bf16x8(float4 a, float4 b) {
  bf16x8 r;
  r[0] = (__bf16)a.x; r[1] = (__bf16)a.y; r[2] = (__bf16)a.z; r[3] = (__bf16)a.w;
  r[4] = (__bf16)b.x; r[5] = (__bf16)b.y; r[6] = (__bf16)b.z; r[7] = (__bf16)b.w;
  return r;
}

__device__ __forceinline__ f32x4 mfma16(bf16x8 a, bf16x8 b, f32x4 c) {
  return __builtin_amdgcn_mfma_f32_16x16x32_bf16(a, b, c, 0, 0, 0);
}

#define GLD16(gsrc, ldst)                                                     \
  __builtin_amdgcn_global_load_lds(                                           \
      (const __attribute__((address_space(1))) void*)(gsrc),                  \
      (__attribute__((address_space(3))) void*)(ldst), 16, 0, 0)

// ---------------- CPB MLP table, l-major: bt[l][h] ----------------
__global__ void cpb_table_lh(const float* __restrict__ rel,
                             const float* __restrict__ W1,
                             const float* __restrict__ b1,
                             const float* __restrict__ W2,
                             float* __restrict__ bt) {
  int i = blockIdx.x * blockDim.x + threadIdx.x;
  if (i >= L2N) return;
  float x = rel[2 * i], y = rel[2 * i + 1];
  float acc[NHEAD];
#pragma unroll
  for (int h = 0; h < NHEAD; ++h) acc[h] = 0.f;
#pragma unroll
  for (int j = 0; j < HIDN; ++j) {
    float t = fmaf(x, W1[j], fmaf(y, W1[HIDN + j], b1[j]));
    float g = 0.5f * t * (1.f + erff(t * 0.70710678118654752f));
#pragma unroll
    for (int h = 0; h < NHEAD; ++h) acc[h] = fmaf(g, W2[j * NHEAD + h], acc[h]);
  }
#pragma unroll
  for (int h = 0; h < NHEAD; ++h) bt[(size_t)i * NHEAD + h] = acc[h];
}

// ---------------- expand masked bias to bf16 [H][S][S] ----------------
__global__ void bias_expand(const int* __restrict__ idx,
                            const float* __restrict__ bt,
                            const int* __restrict__ Rp,
                            __bf16* __restrict__ bias) {
  const int qrow = blockIdx.x;
  const int R = Rp[0];
  const bool qok = (qrow >= R);
  for (int k = threadIdx.x; k < S_LEN; k += blockDim.x) {
    const int l = idx[(size_t)qrow * S_LEN + k];
    const bool on = qok && (k >= R);
    const float4* btv = (const float4*)bt + (size_t)l * 4;
    float va[16];
    *(float4*)&va[0]  = btv[0];
    *(float4*)&va[4]  = btv[1];
    *(float4*)&va[8]  = btv[2];
    *(float4*)&va[12] = btv[3];
#pragma unroll
    for (int h = 0; h < NHEAD; ++h)
      bias[(size_t)h * S_LEN * S_LEN + (size_t)qrow * S_LEN + k] =
          on ? (__bf16)va[h] : (__bf16)0.f;
  }
}

// ---------------- pack K,V to bf16 tiles with permute+swizzle ----------------
// K: Kb[bh][it][rho][c'] = K[kb + e(rho)][c' ^ 8*(rho&7)], e(rho)=((rho&15)<<2)|(rho>>4)
// V: Vb[bh][it][d][c']   = V[kb + (c' ^ 8*(d&7))][d]
__global__ __launch_bounds__(256) void kv_pack(const float* __restrict__ kg,
                                               const float* __restrict__ vg,
                                               __bf16* __restrict__ Kb,
                                               __bf16* __restrict__ Vb) {
  const int it = blockIdx.x, bh = blockIdx.y;
  const int kb = it * KVB;
  const int tid = threadIdx.x;
  const float* kp = kg + (size_t)bh * S_LEN * DH;
  const float* vp = vg + (size_t)bh * S_LEN * DH;
  __bf16* kout = Kb + ((size_t)bh * NKT + it) * TILE_E;
  __bf16* vout = Vb + ((size_t)bh * NKT + it) * TILE_E;

  // K rows: 512 8-elem groups, 2 per thread
  for (int i = tid; i < 512; i += 256) {
    const int rho = i >> 3, gx = i & 7;
    const int e = ((rho & 15) << 2) | (rho >> 4);
    const int key = kb + e;
    const int gsrc = gx ^ (rho & 7);
    float4 a = {0.f, 0.f, 0.f, 0.f}, b = {0.f, 0.f, 0.f, 0.f};
    if (key < S_LEN) {
      a = *(const float4*)(kp + (size_t)key * DH + gsrc * 8);
      b = *(const float4*)(kp + (size_t)key * DH + gsrc * 8 + 4);
    }
    *(bf16x8*)(kout + (size_t)rho * 64 + gx * 8) = cvt_bf16x8(a, b);
  }

  // V: stage tile fp32 into LDS, then transposed+swizzled bf16 out
  __shared__ float vt[64][68];
  for (int i = tid; i < 1024; i += 256) {  // 64 rows x 16 float4
    const int row = i >> 4, c4 = i & 15;
    const int key = kb + row;
    float4 a = {0.f, 0.f, 0.f, 0.f};
    if (key < S_LEN) a = *(const float4*)(vp + (size_t)key * DH + c4 * 4);
    *(float4*)&vt[row][c4 * 4] = a;
  }
  __syncthreads();
  for (int i = tid; i < 512; i += 256) {
    const int d = i >> 3, gx = i & 7;
    const int kg8 = (gx ^ (d & 7)) * 8;
    bf16x8 o;
#pragma unroll
    for (int j = 0; j < 8; ++j) o[j] = (__bf16)vt[kg8 + j][d];
    *(bf16x8*)(vout + (size_t)d * 64 + gx * 8) = o;
  }
}

// ---------------- flash attention v3: packed tiles + async staging ----------
// 256 thr = 4 waves; block = (qt, h, b). Tiles of 64 keys, double-buffered.
// Max-free softmax: p = exp(s), per-lane partial row sums, reduce at end.
__global__ __launch_bounds__(256, 4) void flex_attn_v3(
    const float* __restrict__ qg, const __bf16* __restrict__ Kb,
    const __bf16* __restrict__ Vb, const __bf16* __restrict__ biasG,
    float* __restrict__ out) {
  const int b = blockIdx.z, h = blockIdx.y, qt = blockIdx.x;
  const int bh = b * NHEAD + h;
  const int tid = threadIdx.x;
  const int wave = tid >> 6, lane = tid & 63;
  const int g = lane >> 4, m = lane & 15;

  __shared__ __align__(16) __bf16 Kt[2][KVB][64];   // 16 KB
  __shared__ __align__(16) __bf16 Vt[2][DH][64];    // 16 KB
  __shared__ __align__(16) __bf16 Pl[4][16][64];    // 8 KB

  const __bf16* KbT = Kb + (size_t)bh * NKT * TILE_E;
  const __bf16* VbT = Vb + (size_t)bh * NKT * TILE_E;
  const __bf16* bp = biasG + (size_t)h * S_LEN * S_LEN;
  const float* qp = qg + (size_t)bh * S_LEN * DH;

  // Q fragments, pre-scaled by Dh^-0.5 = 0.125 (exact)
  const int qrow = qt * 64 + wave * 16 + m;
  bf16x8 qf[2];
#pragma unroll
  for (int dc = 0; dc < 2; ++dc) {
    float4 a = {0.f, 0.f, 0.f, 0.f}, bb = {0.f, 0.f, 0.f, 0.f};
    if (qrow < S_LEN) {
      a = *(const float4*)(qp + (size_t)qrow * DH + dc * 32 + g * 8);
      bb = *(const float4*)(qp + (size_t)qrow * DH + dc * 32 + g * 8 + 4);
    }
    a.x *= 0.125f; a.y *= 0.125f; a.z *= 0.125f; a.w *= 0.125f;
    bb.x *= 0.125f; bb.y *= 0.125f; bb.z *= 0.125f; bb.w *= 0.125f;
    qf[dc] = cvt_bf16x8(a, bb);
  }

  const int qb4 = qt * 64 + wave * 16 + g * 4;
  const __bf16* brow[4];
#pragma unroll
  for (int r = 0; r < 4; ++r) {
    int qq = qb4 + r; if (qq > S_LEN - 1) qq = S_LEN - 1;
    brow[r] = bp + (size_t)qq * S_LEN;
  }

  f32x4 acc_o[4];
#pragma unroll
  for (int t = 0; t < 4; ++t) acc_o[t] = (f32x4){0.f, 0.f, 0.f, 0.f};
  float lsum[4] = {0.f, 0.f, 0.f, 0.f};

  const int sw_m = (m & 7) << 3;  // element-index swizzle for rows with row&7==m&7
  const int lo16 = lane * 8;      // elem offset of this lane's 16B in a 1KB chunk

  // --- prologue: stage tile 0 into buf 0 ---
  {
    const __bf16* gk = KbT + wave * 1024 + lo16;
    const __bf16* gv = VbT + wave * 1024 + lo16;
    __bf16* lk = &Kt[0][0][0] + wave * 1024;
    __bf16* lv = &Vt[0][0][0] + wave * 1024;
    GLD16(gk, lk); GLD16(gk + 512, lk + 512);
    GLD16(gv, lv); GLD16(gv + 512, lv + 512);
  }

  for (int it = 0; it < NKT; ++it) {
    const int buf = it & 1;
    const int kb = it * KVB;
    const int kk = kb + 4 * m;
    const bool kvalid = (kk < S_LEN);
    const float kvf = kvalid ? 1.f : 0.f;

    // bias loads for this tile (global, VGPR) — issued early, waited in softmax
    bf16x4 bias4[4];
#pragma unroll
    for (int r = 0; r < 4; ++r) {
      bf16x4 z; z[0] = (__bf16)0.f; z[1] = (__bf16)0.f; z[2] = (__bf16)0.f; z[3] = (__bf16)0.f;
      bias4[r] = kvalid ? *(const bf16x4*)(brow[r] + kk) : z;
    }

    __builtin_amdgcn_s_barrier();  // all waves done reading buf^1 (prev iter)

    // prefetch next tile into buf^1 (wrap on last iter: dummy, keeps vmcnt uniform)
    {
      const int nit = (it + 1 < NKT) ? it + 1 : 0;
      const __bf16* gk = KbT + (size_t)nit * TILE_E + wave * 1024 + lo16;
      const __bf16* gv = VbT + (size_t)nit * TILE_E + wave * 1024 + lo16;
      __bf16* lk = &Kt[buf ^ 1][0][0] + wave * 1024;
      __bf16* lv = &Vt[buf ^ 1][0][0] + wave * 1024;
      GLD16(gk, lk); GLD16(gk + 512, lk + 512);
      GLD16(gv, lv); GLD16(gv + 512, lv + 512);
    }

    // tile-it staging (issued last iter) is 9th+ oldest: wait it out, keep 8 newest in flight
    asm volatile("s_waitcnt vmcnt(8)" ::: "memory");
    __builtin_amdgcn_s_barrier();
    __builtin_amdgcn_sched_barrier(0);

    // ---- QK^T: 4 col tiles x 2 MFMAs (swizzled reads, conflict-free) ----
    f32x4 sc[4];
#pragma unroll
    for (int c = 0; c < 4; ++c) {
      f32x4 a = (f32x4){0.f, 0.f, 0.f, 0.f};
#pragma unroll
      for (int dc = 0; dc < 2; ++dc) {
        bf16x8 kf = *(bf16x8*)&Kt[buf][c * 16 + m][(dc * 32 + g * 8) ^ sw_m];
        a = mfma16(qf[dc], kf, a);
      }
      sc[c] = a;
    }

    // ---- max-free softmax: p = exp(s), no cross-lane ops ----
#pragma unroll
    for (int r = 0; r < 4; ++r) {
      float p0 = __expf(sc[0][r] + (float)bias4[r][0]) * kvf;
      float p1 = __expf(sc[1][r] + (float)bias4[r][1]) * kvf;
      float p2 = __expf(sc[2][r] + (float)bias4[r][2]) * kvf;
      float p3 = __expf(sc[3][r] + (float)bias4[r][3]) * kvf;
      lsum[r] += (p0 + p1) + (p2 + p3);
      bf16x4 pb;
      pb[0] = (__bf16)p0; pb[1] = (__bf16)p1; pb[2] = (__bf16)p2; pb[3] = (__bf16)p3;
      const int row = g * 4 + r;
      *(bf16x4*)&Pl[wave][row][(4 * m) ^ ((row & 7) << 3)] = pb;
    }

    // ---- PV: 2 k-chunks x 4 d-tiles (per-wave P, no barrier) ----
#pragma unroll
    for (int kc = 0; kc < 2; ++kc) {
      bf16x8 pf = *(bf16x8*)&Pl[wave][m][(kc * 32 + g * 8) ^ sw_m];
#pragma unroll
      for (int t = 0; t < 4; ++t) {
        bf16x8 vf = *(bf16x8*)&Vt[buf][t * 16 + m][(kc * 32 + g * 8) ^ sw_m];
        acc_o[t] = mfma16(pf, vf, acc_o[t]);
      }
    }
  }

  // ---- epilogue: reduce lsum across the 16 m-lanes, write O ----
#pragma unroll
  for (int r = 0; r < 4; ++r) {
    float s = lsum[r];
    s += __shfl_xor(s, 1);
    s += __shfl_xor(s, 2);
    s += __shfl_xor(s, 4);
    s += __shfl_xor(s, 8);
    const int qq = qb4 + r;
    if (qq >= S_LEN) continue;
    const float inv = 1.f / s;
    float* op = out + (((size_t)bh) * S_LEN + qq) * DH;
#pragma unroll
    for (int t = 0; t < 4; ++t) op[t * 16 + m] = acc_o[t][r] * inv;
  }
}

// ================= fallback: round-2 fast path (ws >= bt+bias only) =========
__global__ __launch_bounds__(256, 4) void flex_attn_fast(
    const float* __restrict__ qg, const float* __restrict__ kg,
    const float* __restrict__ vg, const __bf16* __restrict__ biasG,
    float* __restrict__ out) {
  const int b = blockIdx.z, h = blockIdx.y, qt = blockIdx.x;
  const int tid = threadIdx.x;
  const int wave = tid >> 6, lane = tid & 63;
  const int g = lane >> 4, m = lane & 15;

  __shared__ __align__(16) __bf16 Kt[KVB][72];
  __shared__ __align__(16) __bf16 Vt[DH][72];
  __shared__ __align__(16) __bf16 Pl[4][16][72];

  const size_t base = ((size_t)(b * NHEAD + h)) * S_LEN * DH;
  const float* qp = qg + base;
  const float* kp = kg + base;
  const float* vp = vg + base;
  const __bf16* bp = biasG + (size_t)h * S_LEN * S_LEN;

  const int qrow = qt * 64 + wave * 16 + m;
  bf16x8 qf[2];
#pragma unroll
  for (int dc = 0; dc < 2; ++dc) {
    float4 a = {0.f, 0.f, 0.f, 0.f}, bb = {0.f, 0.f, 0.f, 0.f};
    if (qrow < S_LEN) {
      a = *(const float4*)(qp + (size_t)qrow * DH + dc * 32 + g * 8);
      bb = *(const float4*)(qp + (size_t)qrow * DH + dc * 32 + g * 8 + 4);
    }
    a.x *= 0.125f; a.y *= 0.125f; a.z *= 0.125f; a.w *= 0.125f;
    bb.x *= 0.125f; bb.y *= 0.125f; bb.z *= 0.125f; bb.w *= 0.125f;
    qf[dc] = cvt_bf16x8(a, bb);
  }

  f32x4 acc_o[4];
#pragma unroll
  for (int t = 0; t < 4; ++t) acc_o[t] = (f32x4){0.f, 0.f, 0.f, 0.f};
  float mrow[4], lrow[4];
#pragma unroll
  for (int r = 0; r < 4; ++r) { mrow[r] = -1e30f; lrow[r] = 0.f; }

  const int qb4 = qt * 64 + wave * 16 + g * 4;
  const int eK = wave * 16 + (lane >> 2);
  const int rowK = ((eK & 3) << 4) | (eK >> 2);
  const int colK = (lane & 3) * 16;

  for (int it = 0; it < NKT; ++it) {
    const int kb = it * KVB;
    __syncthreads();
    {
      const int krow = kb + eK;
      float4 a0 = {0,0,0,0}, a1 = {0,0,0,0}, a2 = {0,0,0,0}, a3 = {0,0,0,0};
      if (krow < S_LEN) {
        const float* src = kp + (size_t)krow * DH + colK;
        a0 = *(const float4*)(src);
        a1 = *(const float4*)(src + 4);
        a2 = *(const float4*)(src + 8);
        a3 = *(const float4*)(src + 12);
      }
      *(bf16x8*)&Kt[rowK][colK] = cvt_bf16x8(a0, a1);
      *(bf16x8*)&Kt[rowK][colK + 8] = cvt_bf16x8(a2, a3);
    }
    {
      bf16x8 p0, p1;
#pragma unroll
      for (int t = 0; t < 8; ++t) {
        const int kr = kb + wave * 16 + t;
        p0[t] = (kr < S_LEN) ? (__bf16)vp[(size_t)kr * DH + lane] : (__bf16)0.f;
      }
#pragma unroll
      for (int t = 0; t < 8; ++t) {
        const int kr = kb + wave * 16 + 8 + t;
        p1[t] = (kr < S_LEN) ? (__bf16)vp[(size_t)kr * DH + lane] : (__bf16)0.f;
      }
      *(bf16x8*)&Vt[lane][wave * 16] = p0;
      *(bf16x8*)&Vt[lane][wave * 16 + 8] = p1;
    }

    const int kk = kb + 4 * m;
    const bool kvalid = (kk < S_LEN);
    bf16x4 bias4[4];
#pragma unroll
    for (int r = 0; r < 4; ++r) {
      const int qq = (qb4 + r < S_LEN) ? qb4 + r : S_LEN - 1;
      bf16x4 z; z[0] = (__bf16)0.f; z[1] = (__bf16)0.f; z[2] = (__bf16)0.f; z[3] = (__bf16)0.f;
      bias4[r] = kvalid ? *(const bf16x4*)(bp + (size_t)qq * S_LEN + kk) : z;
    }

    __syncthreads();

    f32x4 sc[4];
#pragma unroll
    for (int c = 0; c < 4; ++c) {
      f32x4 a = (f32x4){0.f, 0.f, 0.f, 0.f};
#pragma unroll
      for (int dc = 0; dc < 2; ++dc) {
        bf16x8 kf = *(bf16x8*)&Kt[c * 16 + m][dc * 32 + g * 8];
        a = mfma16(qf[dc], kf, a);
      }
      sc[c] = a;
    }

#pragma unroll
    for (int r = 0; r < 4; ++r) {
      float s[4];
#pragma unroll
      for (int c = 0; c < 4; ++c)
        s[c] = kvalid ? sc[c][r] + (float)bias4[r][c] : -1e30f;
      float mx = fmaxf(fmaxf(s[0], s[1]), fmaxf(s[2], s[3]));
      mx = fmaxf(mx, __shfl_xor(mx, 1));
      mx = fmaxf(mx, __shfl_xor(mx, 2));
      mx = fmaxf(mx, __shfl_xor(mx, 4));
      mx = fmaxf(mx, __shfl_xor(mx, 8));
      const float mnew = fmaxf(mrow[r], mx);
      const float alpha = __expf(mrow[r] - mnew);
      float p0 = __expf(s[0] - mnew), p1 = __expf(s[1] - mnew);
      float p2 = __expf(s[2] - mnew), p3 = __expf(s[3] - mnew);
      float sum = (p0 + p1) + (p2 + p3);
      sum += __shfl_xor(sum, 1);
      sum += __shfl_xor(sum, 2);
      sum += __shfl_xor(sum, 4);
      sum += __shfl_xor(sum, 8);
      lrow[r] = lrow[r] * alpha + sum;
      mrow[r] = mnew;
      bf16x4 pb;
      pb[0] = (__bf16)p0; pb[1] = (__bf16)p1; pb[2] = (__bf16)p2; pb[3] = (__bf16)p3;
      *(bf16x4*)&Pl[wave][g * 4 + r][4 * m] = pb;
#pragma unroll
      for (int t = 0; t < 4; ++t) acc_o[t][r] *= alpha;
    }

#pragma unroll
    for (int kc = 0; kc < 2; ++kc) {
      bf16x8 pf = *(bf16x8*)&Pl[wave][m][kc * 32 + g * 8];
#pragma unroll
      for (int t = 0; t < 4; ++t) {
        bf16x8 vf = *(bf16x8*)&Vt[t * 16 + m][kc * 32 + g * 8];
        acc_o[t] = mfma16(pf, vf, acc_o[t]);
      }
    }
  }

#pragma unroll
  for (int r = 0; r < 4; ++r) {
    const int qq = qb4 + r;
    if (qq >= S_LEN) continue;
    const float inv = 1.f / lrow[r];
    float* op = out + (((size_t)(b * NHEAD + h)) * S_LEN + qq) * DH;
#pragma unroll
    for (int t = 0; t < 4; ++t) op[t * 16 + m] = acc_o[t][r] * inv;
  }
}

extern "C" void kernel_launch(void* const* d_in, const int* in_sizes, int n_in,
                              void* d_out, int out_size, void* d_ws, size_t ws_size,
                              hipStream_t stream) {
  const float* q = (const float*)d_in[0];
  const float* k = (const float*)d_in[1];
  const float* v = (const float*)d_in[2];
  const float* rel = (const float*)d_in[3];
  const float* W1 = (const float*)d_in[4];
  const float* b1 = (const float*)d_in[5];
  const float* W2 = (const float*)d_in[6];
  const int* idx = (const int*)d_in[7];
  const int* Rp = (const int*)d_in[8];
  float* out = (float*)d_out;

  const size_t bt_bytes = 1u << 18;                                // 256 KB slot
  const size_t bias_bytes = (size_t)NHEAD * S_LEN * S_LEN * 2;     // 33.8 MB
  const size_t kv_bytes = (size_t)NBATCH * NHEAD * NKT * TILE_E * 2;  // 17.8 MB each

  if (ws_size >= bt_bytes + bias_bytes + 2 * kv_bytes) {
    float* bt = (float*)d_ws;
    __bf16* bias = (__bf16*)((char*)d_ws + bt_bytes);
    __bf16* Kb = (__bf16*)((char*)d_ws + bt_bytes + bias_bytes);
    __bf16* Vb = (__bf16*)((char*)d_ws + bt_bytes + bias_bytes + kv_bytes);
    cpb_table_lh<<<dim3((L2N + 255) / 256), dim3(256), 0, stream>>>(rel, W1, b1, W2, bt);
    bias_expand<<<dim3(S_LEN), dim3(256), 0, stream>>>(idx, bt, Rp, bias);
    kv_pack<<<dim3(NKT, NBATCH * NHEAD), dim3(256), 0, stream>>>(k, v, Kb, Vb);
    flex_attn_v3<<<dim3(NQT, NHEAD, NBATCH), dim3(256), 0, stream>>>(q, Kb, Vb, bias, out);
  } else {
    float* bt = (float*)d_ws;
    __bf16* bias = (__bf16*)((char*)d_ws + bt_bytes);
    cpb_table_lh<<<dim3((L2N + 255) / 256), dim3(256), 0, stream>>>(rel, W1, b1, W2, bt);
    bias_expand<<<dim3(S_LEN), dim3(256), 0, stream>>>(idx, bt, Rp, bias);
    flex_attn_fast<<<dim3(NQT, NHEAD, NBATCH), dim3(256), 0, stream>>>(q, k, v, bias, out);
  }
}

// Round 5
// 276.746 us; speedup vs baseline: 2.9656x; 1.0109x over previous
//
#include <hip/hip_runtime.h>
#include <hip/hip_bf16.h>

#define S_LEN 1028
#define DH 64
#define NHEAD 16
#define NBATCH 8
#define L2N 3969
#define HIDN 32
#define KVB 64
#define NKT 17
#define NQT 17
#define TILE_E 4096  // 64x64 elems per packed tile
#define LOG2E 1.4426950408889634f

typedef __bf16 bf16x8 __attribute__((ext_vector_type(8)));
typedef __bf16 bf16x4 __attribute__((ext_vector_type(4)));
typedef float f32x4 __attribute__((ext_vector_type(4)));

__device__ __forceinline__ bf16x8 cvt_bf16x8(float4 a, float4 b) {
  bf16x8 r;
  r[0] = (__bf16)a.x; r[1] = (__bf16)a.y; r[2] = (__bf16)a.z; r[3] = (__bf16)a.w;
  r[4] = (__bf16)b.x; r[5] = (__bf16)b.y; r[6] = (__bf16)b.z; r[7] = (__bf16)b.w;
  return r;
}

__device__ __forceinline__ f32x4 mfma16(bf16x8 a, bf16x8 b, f32x4 c) {
  return __builtin_amdgcn_mfma_f32_16x16x32_bf16(a, b, c, 0, 0, 0);
}

__device__ __forceinline__ float exp2_fast(float x) {
#if __has_builtin(__builtin_amdgcn_exp2f)
  return __builtin_amdgcn_exp2f(x);
#else
  return __expf(x * 0.6931471805599453f);
#endif
}

#define GLD16(gsrc, ldst)                                                     \
  __builtin_amdgcn_global_load_lds(                                           \
      (const __attribute__((address_space(1))) void*)(gsrc),                  \
      (__attribute__((address_space(3))) void*)(ldst), 16, 0, 0)

// ---------------- CPB MLP table, l-major: bt[l][h] ----------------
__global__ void cpb_table_lh(const float* __restrict__ rel,
                             const float* __restrict__ W1,
                             const float* __restrict__ b1,
                             const float* __restrict__ W2,
                             float* __restrict__ bt) {
  int i = blockIdx.x * blockDim.x + threadIdx.x;
  if (i >= L2N) return;
  float x = rel[2 * i], y = rel[2 * i + 1];
  float acc[NHEAD];
#pragma unroll
  for (int h = 0; h < NHEAD; ++h) acc[h] = 0.f;
#pragma unroll
  for (int j = 0; j < HIDN; ++j) {
    float t = fmaf(x, W1[j], fmaf(y, W1[HIDN + j], b1[j]));
    float g = 0.5f * t * (1.f + erff(t * 0.70710678118654752f));
#pragma unroll
    for (int h = 0; h < NHEAD; ++h) acc[h] = fmaf(g, W2[j * NHEAD + h], acc[h]);
  }
#pragma unroll
  for (int h = 0; h < NHEAD; ++h) bt[(size_t)i * NHEAD + h] = acc[h];
}

// ---------------- expand masked bias (log2e-scaled) to bf16 [H][S][S] -------
// Strip-mined through LDS so stores are coalesced 32B/thread.
__global__ __launch_bounds__(256) void bias_expand2(const int* __restrict__ idx,
                                                    const float* __restrict__ bt,
                                                    const int* __restrict__ Rp,
                                                    __bf16* __restrict__ bias) {
  const int qrow = blockIdx.x;
  const int R = Rp[0];
  const bool qok = (qrow >= R);
  const int tid = threadIdx.x;
  __shared__ __align__(16) __bf16 strip[NHEAD][264];

  for (int k0 = 0; k0 < 1024; k0 += 256) {
    const int k = k0 + tid;
    const int l = idx[(size_t)qrow * S_LEN + k];
    const bool on = qok && (k >= R);
    const float4* btv = (const float4*)bt + (size_t)l * 4;
    float va[16];
    *(float4*)&va[0]  = btv[0];
    *(float4*)&va[4]  = btv[1];
    *(float4*)&va[8]  = btv[2];
    *(float4*)&va[12] = btv[3];
#pragma unroll
    for (int h = 0; h < NHEAD; ++h)
      strip[h][tid] = on ? (__bf16)(va[h] * LOG2E) : (__bf16)0.f;
    __syncthreads();
    // write-out: thread t -> head t>>4, 16 consecutive k at (t&15)*16
    {
      const int h = tid >> 4, kg = tid & 15;
      bf16x8 w0 = *(bf16x8*)&strip[h][kg * 16];
      bf16x8 w1 = *(bf16x8*)&strip[h][kg * 16 + 8];
      __bf16* dst = bias + (size_t)h * S_LEN * S_LEN + (size_t)qrow * S_LEN + k0 + kg * 16;
      *(bf16x8*)dst = w0;
      *(bf16x8*)(dst + 8) = w1;
    }
    __syncthreads();
  }
  // tail: k = 1024..1027
  if (tid < 64) {
    const int kt = tid & 3, h = tid >> 2;
    const int k = 1024 + kt;
    const int l = idx[(size_t)qrow * S_LEN + k];
    const bool on = qok && (k >= R);
    const float v = bt[(size_t)l * NHEAD + h];
    bias[(size_t)h * S_LEN * S_LEN + (size_t)qrow * S_LEN + k] =
        on ? (__bf16)(v * LOG2E) : (__bf16)0.f;
  }
}

// ---------------- pack K,V to bf16 tiles with permute+swizzle ----------------
// K: Kb[bh][it][rho][c'] = K[kb + e(rho)][c' ^ 8*(rho&7)], e(rho)=((rho&15)<<2)|(rho>>4)
// V: Vb[bh][it][d][c']   = V[kb + (c' ^ 8*(d&7))][d]
__global__ __launch_bounds__(256) void kv_pack(const float* __restrict__ kg,
                                               const float* __restrict__ vg,
                                               __bf16* __restrict__ Kb,
                                               __bf16* __restrict__ Vb) {
  const int it = blockIdx.x, bh = blockIdx.y;
  const int kb = it * KVB;
  const int tid = threadIdx.x;
  const float* kp = kg + (size_t)bh * S_LEN * DH;
  const float* vp = vg + (size_t)bh * S_LEN * DH;
  __bf16* kout = Kb + ((size_t)bh * NKT + it) * TILE_E;
  __bf16* vout = Vb + ((size_t)bh * NKT + it) * TILE_E;

  for (int i = tid; i < 512; i += 256) {
    const int rho = i >> 3, gx = i & 7;
    const int e = ((rho & 15) << 2) | (rho >> 4);
    const int key = kb + e;
    const int gsrc = gx ^ (rho & 7);
    float4 a = {0.f, 0.f, 0.f, 0.f}, b = {0.f, 0.f, 0.f, 0.f};
    if (key < S_LEN) {
      a = *(const float4*)(kp + (size_t)key * DH + gsrc * 8);
      b = *(const float4*)(kp + (size_t)key * DH + gsrc * 8 + 4);
    }
    *(bf16x8*)(kout + (size_t)rho * 64 + gx * 8) = cvt_bf16x8(a, b);
  }

  __shared__ float vt[64][68];
  for (int i = tid; i < 1024; i += 256) {
    const int row = i >> 4, c4 = i & 15;
    const int key = kb + row;
    float4 a = {0.f, 0.f, 0.f, 0.f};
    if (key < S_LEN) a = *(const float4*)(vp + (size_t)key * DH + c4 * 4);
    *(float4*)&vt[row][c4 * 4] = a;
  }
  __syncthreads();
  for (int i = tid; i < 512; i += 256) {
    const int d = i >> 3, gx = i & 7;
    const int kg8 = (gx ^ (d & 7)) * 8;
    bf16x8 o;
#pragma unroll
    for (int j = 0; j < 8; ++j) o[j] = (__bf16)vt[kg8 + j][d];
    *(bf16x8*)(vout + (size_t)d * 64 + gx * 8) = o;
  }
}

// ---------------- flash attention v4 ----------------------------------------
// exp2 domain; bias as MFMA C-init; masked tail peeled; double-buffered
// global_load_lds staging with counted vmcnt.
#define TILE_STEP(ITC, MASKED) do {                                           \
    const int buf_ = (ITC) & 1;                                               \
    const int kk_ = (ITC) * KVB + 4 * m;                                      \
    bf16x4 bias4_[4];                                                         \
    _Pragma("unroll")                                                         \
    for (int r = 0; r < 4; ++r) {                                             \
      bf16x4 z_; z_[0] = (__bf16)0.f; z_[1] = (__bf16)0.f;                    \
      z_[2] = (__bf16)0.f; z_[3] = (__bf16)0.f;                               \
      bias4_[r] = (!(MASKED) || kk_ < S_LEN)                                  \
                      ? *(const bf16x4*)(brow[r] + kk_) : z_;                 \
    }                                                                         \
    __builtin_amdgcn_s_barrier();                                             \
    {                                                                         \
      const int nit_ = ((ITC) + 1 < NKT) ? (ITC) + 1 : 0;                     \
      const __bf16* gk_ = KbT + (size_t)nit_ * TILE_E + wave * 1024 + lo16;   \
      const __bf16* gv_ = VbT + (size_t)nit_ * TILE_E + wave * 1024 + lo16;   \
      __bf16* lk_ = &Kt[buf_ ^ 1][0][0] + wave * 1024;                        \
      __bf16* lv_ = &Vt[buf_ ^ 1][0][0] + wave * 1024;                        \
      GLD16(gk_, lk_); GLD16(gk_ + 512, lk_ + 512);                           \
      GLD16(gv_, lv_); GLD16(gv_ + 512, lv_ + 512);                           \
    }                                                                         \
    asm volatile("s_waitcnt vmcnt(8)" ::: "memory");                          \
    __builtin_amdgcn_s_barrier();                                             \
    __builtin_amdgcn_sched_barrier(0);                                        \
    f32x4 sc_[4];                                                             \
    _Pragma("unroll")                                                         \
    for (int c = 0; c < 4; ++c) {                                             \
      f32x4 a_;                                                               \
      _Pragma("unroll")                                                       \
      for (int r = 0; r < 4; ++r) a_[r] = (float)bias4_[r][c];                \
      _Pragma("unroll")                                                       \
      for (int dc = 0; dc < 2; ++dc) {                                        \
        bf16x8 kf_ = *(bf16x8*)&Kt[buf_][c * 16 + m][(dc * 32 + g * 8) ^ sw_m]; \
        a_ = mfma16(qf[dc], kf_, a_);                                         \
      }                                                                       \
      sc_[c] = a_;                                                            \
    }                                                                         \
    _Pragma("unroll")                                                         \
    for (int r = 0; r < 4; ++r) {                                             \
      float p0_ = exp2_fast(sc_[0][r]);                                       \
      float p1_ = exp2_fast(sc_[1][r]);                                       \
      float p2_ = exp2_fast(sc_[2][r]);                                       \
      float p3_ = exp2_fast(sc_[3][r]);                                       \
      if (MASKED) {                                                           \
        const float kvf_ = (kk_ < S_LEN) ? 1.f : 0.f;                         \
        lsum[r] += kvf_ * ((p0_ + p1_) + (p2_ + p3_));                        \
      } else {                                                                \
        lsum[r] += (p0_ + p1_) + (p2_ + p3_);                                 \
      }                                                                       \
      bf16x4 pb_;                                                             \
      pb_[0] = (__bf16)p0_; pb_[1] = (__bf16)p1_;                             \
      pb_[2] = (__bf16)p2_; pb_[3] = (__bf16)p3_;                             \
      const int row_ = g * 4 + r;                                             \
      *(bf16x4*)&Pl[wave][row_][(4 * m) ^ ((row_ & 7) << 3)] = pb_;           \
    }                                                                         \
    _Pragma("unroll")                                                         \
    for (int kc = 0; kc < 2; ++kc) {                                          \
      bf16x8 pf_ = *(bf16x8*)&Pl[wave][m][(kc * 32 + g * 8) ^ sw_m];          \
      _Pragma("unroll")                                                       \
      for (int t = 0; t < 4; ++t) {                                           \
        bf16x8 vf_ = *(bf16x8*)&Vt[buf_][t * 16 + m][(kc * 32 + g * 8) ^ sw_m]; \
        acc_o[t] = mfma16(pf_, vf_, acc_o[t]);                                \
      }                                                                       \
    }                                                                         \
  } while (0)

__global__ __launch_bounds__(256, 4) void flex_attn_v4(
    const float* __restrict__ qg, const __bf16* __restrict__ Kb,
    const __bf16* __restrict__ Vb, const __bf16* __restrict__ biasG,
    float* __restrict__ out) {
  const int b = blockIdx.z, h = blockIdx.y, qt = blockIdx.x;
  const int bh = b * NHEAD + h;
  const int tid = threadIdx.x;
  const int wave = tid >> 6, lane = tid & 63;
  const int g = lane >> 4, m = lane & 15;

  __shared__ __align__(16) __bf16 Kt[2][KVB][64];   // 16 KB
  __shared__ __align__(16) __bf16 Vt[2][DH][64];    // 16 KB
  __shared__ __align__(16) __bf16 Pl[4][16][64];    // 8 KB

  const __bf16* KbT = Kb + (size_t)bh * NKT * TILE_E;
  const __bf16* VbT = Vb + (size_t)bh * NKT * TILE_E;
  const __bf16* bp = biasG + (size_t)h * S_LEN * S_LEN;
  const float* qp = qg + (size_t)bh * S_LEN * DH;

  // Q fragments, pre-scaled by Dh^-0.5 * log2(e)
  const int qrow = qt * 64 + wave * 16 + m;
  const float qs = 0.125f * LOG2E;
  bf16x8 qf[2];
#pragma unroll
  for (int dc = 0; dc < 2; ++dc) {
    float4 a = {0.f, 0.f, 0.f, 0.f}, bb = {0.f, 0.f, 0.f, 0.f};
    if (qrow < S_LEN) {
      a = *(const float4*)(qp + (size_t)qrow * DH + dc * 32 + g * 8);
      bb = *(const float4*)(qp + (size_t)qrow * DH + dc * 32 + g * 8 + 4);
    }
    a.x *= qs; a.y *= qs; a.z *= qs; a.w *= qs;
    bb.x *= qs; bb.y *= qs; bb.z *= qs; bb.w *= qs;
    qf[dc] = cvt_bf16x8(a, bb);
  }

  const int qb4 = qt * 64 + wave * 16 + g * 4;
  const __bf16* brow[4];
#pragma unroll
  for (int r = 0; r < 4; ++r) {
    int qq = qb4 + r; if (qq > S_LEN - 1) qq = S_LEN - 1;
    brow[r] = bp + (size_t)qq * S_LEN;
  }

  f32x4 acc_o[4];
#pragma unroll
  for (int t = 0; t < 4; ++t) acc_o[t] = (f32x4){0.f, 0.f, 0.f, 0.f};
  float lsum[4] = {0.f, 0.f, 0.f, 0.f};

  const int sw_m = (m & 7) << 3;
  const int lo16 = lane * 8;

  // prologue: stage tile 0 into buf 0
  {
    const __bf16* gk = KbT + wave * 1024 + lo16;
    const __bf16* gv = VbT + wave * 1024 + lo16;
    __bf16* lk = &Kt[0][0][0] + wave * 1024;
    __bf16* lv = &Vt[0][0][0] + wave * 1024;
    GLD16(gk, lk); GLD16(gk + 512, lk + 512);
    GLD16(gv, lv); GLD16(gv + 512, lv + 512);
  }

#pragma unroll 2
  for (int it = 0; it < 16; ++it) {
    TILE_STEP(it, false);
  }
  TILE_STEP(16, true);

  // epilogue: reduce lsum across the 16 m-lanes, write O
#pragma unroll
  for (int r = 0; r < 4; ++r) {
    float s = lsum[r];
    s += __shfl_xor(s, 1);
    s += __shfl_xor(s, 2);
    s += __shfl_xor(s, 4);
    s += __shfl_xor(s, 8);
    const int qq = qb4 + r;
    if (qq >= S_LEN) continue;
    const float inv = 1.f / s;
    float* op = out + (((size_t)bh) * S_LEN + qq) * DH;
#pragma unroll
    for (int t = 0; t < 4; ++t) op[t * 16 + m] = acc_o[t][r] * inv;
  }
}

// ================= fallback (ws too small for packed KV): exp2 domain =======
__global__ __launch_bounds__(256, 4) void flex_attn_fast(
    const float* __restrict__ qg, const float* __restrict__ kg,
    const float* __restrict__ vg, const __bf16* __restrict__ biasG,
    float* __restrict__ out) {
  const int b = blockIdx.z, h = blockIdx.y, qt = blockIdx.x;
  const int tid = threadIdx.x;
  const int wave = tid >> 6, lane = tid & 63;
  const int g = lane >> 4, m = lane & 15;

  __shared__ __align__(16) __bf16 Kt[KVB][72];
  __shared__ __align__(16) __bf16 Vt[DH][72];
  __shared__ __align__(16) __bf16 Pl[4][16][72];

  const size_t base = ((size_t)(b * NHEAD + h)) * S_LEN * DH;
  const float* qp = qg + base;
  const float* kp = kg + base;
  const float* vp = vg + base;
  const __bf16* bp = biasG + (size_t)h * S_LEN * S_LEN;

  const int qrow = qt * 64 + wave * 16 + m;
  const float qs = 0.125f * LOG2E;
  bf16x8 qf[2];
#pragma unroll
  for (int dc = 0; dc < 2; ++dc) {
    float4 a = {0.f, 0.f, 0.f, 0.f}, bb = {0.f, 0.f, 0.f, 0.f};
    if (qrow < S_LEN) {
      a = *(const float4*)(qp + (size_t)qrow * DH + dc * 32 + g * 8);
      bb = *(const float4*)(qp + (size_t)qrow * DH + dc * 32 + g * 8 + 4);
    }
    a.x *= qs; a.y *= qs; a.z *= qs; a.w *= qs;
    bb.x *= qs; bb.y *= qs; bb.z *= qs; bb.w *= qs;
    qf[dc] = cvt_bf16x8(a, bb);
  }

  f32x4 acc_o[4];
#pragma unroll
  for (int t = 0; t < 4; ++t) acc_o[t] = (f32x4){0.f, 0.f, 0.f, 0.f};
  float mrow[4], lrow[4];
#pragma unroll
  for (int r = 0; r < 4; ++r) { mrow[r] = -1e30f; lrow[r] = 0.f; }

  const int qb4 = qt * 64 + wave * 16 + g * 4;
  const int eK = wave * 16 + (lane >> 2);
  const int rowK = ((eK & 3) << 4) | (eK >> 2);
  const int colK = (lane & 3) * 16;

  for (int it = 0; it < NKT; ++it) {
    const int kb = it * KVB;
    __syncthreads();
    {
      const int krow = kb + eK;
      float4 a0 = {0,0,0,0}, a1 = {0,0,0,0}, a2 = {0,0,0,0}, a3 = {0,0,0,0};
      if (krow < S_LEN) {
        const float* src = kp + (size_t)krow * DH + colK;
        a0 = *(const float4*)(src);
        a1 = *(const float4*)(src + 4);
        a2 = *(const float4*)(src + 8);
        a3 = *(const float4*)(src + 12);
      }
      *(bf16x8*)&Kt[rowK][colK] = cvt_bf16x8(a0, a1);
      *(bf16x8*)&Kt[rowK][colK + 8] = cvt_bf16x8(a2, a3);
    }
    {
      bf16x8 p0, p1;
#pragma unroll
      for (int t = 0; t < 8; ++t) {
        const int kr = kb + wave * 16 + t;
        p0[t] = (kr < S_LEN) ? (__bf16)vp[(size_t)kr * DH + lane] : (__bf16)0.f;
      }
#pragma unroll
      for (int t = 0; t < 8; ++t) {
        const int kr = kb + wave * 16 + 8 + t;
        p1[t] = (kr < S_LEN) ? (__bf16)vp[(size_t)kr * DH + lane] : (__bf16)0.f;
      }
      *(bf16x8*)&Vt[lane][wave * 16] = p0;
      *(bf16x8*)&Vt[lane][wave * 16 + 8] = p1;
    }

    const int kk = kb + 4 * m;
    const bool kvalid = (kk < S_LEN);
    bf16x4 bias4[4];
#pragma unroll
    for (int r = 0; r < 4; ++r) {
      const int qq = (qb4 + r < S_LEN) ? qb4 + r : S_LEN - 1;
      bf16x4 z; z[0] = (__bf16)0.f; z[1] = (__bf16)0.f; z[2] = (__bf16)0.f; z[3] = (__bf16)0.f;
      bias4[r] = kvalid ? *(const bf16x4*)(bp + (size_t)qq * S_LEN + kk) : z;
    }

    __syncthreads();

    f32x4 sc[4];
#pragma unroll
    for (int c = 0; c < 4; ++c) {
      f32x4 a = (f32x4){0.f, 0.f, 0.f, 0.f};
#pragma unroll
      for (int dc = 0; dc < 2; ++dc) {
        bf16x8 kf = *(bf16x8*)&Kt[c * 16 + m][dc * 32 + g * 8];
        a = mfma16(qf[dc], kf, a);
      }
      sc[c] = a;
    }

#pragma unroll
    for (int r = 0; r < 4; ++r) {
      float s[4];
#pragma unroll
      for (int c = 0; c < 4; ++c)
        s[c] = kvalid ? sc[c][r] + (float)bias4[r][c] : -1e30f;
      float mx = fmaxf(fmaxf(s[0], s[1]), fmaxf(s[2], s[3]));
      mx = fmaxf(mx, __shfl_xor(mx, 1));
      mx = fmaxf(mx, __shfl_xor(mx, 2));
      mx = fmaxf(mx, __shfl_xor(mx, 4));
      mx = fmaxf(mx, __shfl_xor(mx, 8));
      const float mnew = fmaxf(mrow[r], mx);
      const float alpha = exp2_fast(mrow[r] - mnew);
      float p0 = exp2_fast(s[0] - mnew), p1 = exp2_fast(s[1] - mnew);
      float p2 = exp2_fast(s[2] - mnew), p3 = exp2_fast(s[3] - mnew);
      float sum = (p0 + p1) + (p2 + p3);
      sum += __shfl_xor(sum, 1);
      sum += __shfl_xor(sum, 2);
      sum += __shfl_xor(sum, 4);
      sum += __shfl_xor(sum, 8);
      lrow[r] = lrow[r] * alpha + sum;
      mrow[r] = mnew;
      bf16x4 pb;
      pb[0] = (__bf16)p0; pb[1] = (__bf16)p1; pb[2] = (__bf16)p2; pb[3] = (__bf16)p3;
      *(bf16x4*)&Pl[wave][g * 4 + r][4 * m] = pb;
#pragma unroll
      for (int t = 0; t < 4; ++t) acc_o[t][r] *= alpha;
    }

#pragma unroll
    for (int kc = 0; kc < 2; ++kc) {
      bf16x8 pf = *(bf16x8*)&Pl[wave][m][kc * 32 + g * 8];
#pragma unroll
      for (int t = 0; t < 4; ++t) {
        bf16x8 vf = *(bf16x8*)&Vt[t * 16 + m][kc * 32 + g * 8];
        acc_o[t] = mfma16(pf, vf, acc_o[t]);
      }
    }
  }

#pragma unroll
  for (int r = 0; r < 4; ++r) {
    const int qq = qb4 + r;
    if (qq >= S_LEN) continue;
    const float inv = 1.f / lrow[r];
    float* op = out + (((size_t)(b * NHEAD + h)) * S_LEN + qq) * DH;
#pragma unroll
    for (int t = 0; t < 4; ++t) op[t * 16 + m] = acc_o[t][r] * inv;
  }
}

extern "C" void kernel_launch(void* const* d_in, const int* in_sizes, int n_in,
                              void* d_out, int out_size, void* d_ws, size_t ws_size,
                              hipStream_t stream) {
  const float* q = (const float*)d_in[0];
  const float* k = (const float*)d_in[1];
  const float* v = (const float*)d_in[2];
  const float* rel = (const float*)d_in[3];
  const float* W1 = (const float*)d_in[4];
  const float* b1 = (const float*)d_in[5];
  const float* W2 = (const float*)d_in[6];
  const int* idx = (const int*)d_in[7];
  const int* Rp = (const int*)d_in[8];
  float* out = (float*)d_out;

  const size_t bt_bytes = 1u << 18;                                // 256 KB slot
  const size_t bias_bytes = (size_t)NHEAD * S_LEN * S_LEN * 2;     // 33.8 MB
  const size_t kv_bytes = (size_t)NBATCH * NHEAD * NKT * TILE_E * 2;  // 17.8 MB each

  if (ws_size >= bt_bytes + bias_bytes + 2 * kv_bytes) {
    float* bt = (float*)d_ws;
    __bf16* bias = (__bf16*)((char*)d_ws + bt_bytes);
    __bf16* Kb = (__bf16*)((char*)d_ws + bt_bytes + bias_bytes);
    __bf16* Vb = (__bf16*)((char*)d_ws + bt_bytes + bias_bytes + kv_bytes);
    cpb_table_lh<<<dim3((L2N + 255) / 256), dim3(256), 0, stream>>>(rel, W1, b1, W2, bt);
    bias_expand2<<<dim3(S_LEN), dim3(256), 0, stream>>>(idx, bt, Rp, bias);
    kv_pack<<<dim3(NKT, NBATCH * NHEAD), dim3(256), 0, stream>>>(k, v, Kb, Vb);
    flex_attn_v4<<<dim3(NQT, NHEAD, NBATCH), dim3(256), 0, stream>>>(q, Kb, Vb, bias, out);
  } else {
    float* bt = (float*)d_ws;
    __bf16* bias = (__bf16*)((char*)d_ws + bt_bytes);
    cpb_table_lh<<<dim3((L2N + 255) / 256), dim3(256), 0, stream>>>(rel, W1, b1, W2, bt);
    bias_expand2<<<dim3(S_LEN), dim3(256), 0, stream>>>(idx, bt, Rp, bias);
    flex_attn_fast<<<dim3(NQT, NHEAD, NBATCH), dim3(256), 0, stream>>>(q, k, v, bias, out);
  }
}